// Round 9
// baseline (162.215 us; speedup 1.0000x reference)
//
#include <hip/hip_runtime.h>
#include <hip/hip_bf16.h>
#include <cstdint>

// MQA: B=4, S=2048, HIDDEN=1024, HEADS=16, HEAD_DIM=64
#define HIDDEN 1024
#define HEADS 16
#define HEAD_DIM 64
#define BB 4
#define SS 2048
#define NTOK (BB * SS)  // 8192

typedef __attribute__((ext_vector_type(8))) __bf16 bf16x8;
typedef __attribute__((ext_vector_type(4))) float f32x4;
typedef unsigned short u16;

// softmax scale folded into Q at projection time: log2(e)/sqrt(HEAD_DIM)
#define PSCALE 0.1803368801111137f

__device__ __forceinline__ u16 f2bf(float x) {
    union { float f; uint32_t u; } v; v.f = x;
    uint32_t r = v.u + 0x7FFF + ((v.u >> 16) & 1);  // RNE
    return (u16)(r >> 16);
}

typedef __attribute__((address_space(3))) uint32_t lds_u32;
typedef __attribute__((address_space(1))) uint32_t glb_u32;
__device__ __forceinline__ void gload16(const u16* g, u16* l) {
    __builtin_amdgcn_global_load_lds((const glb_u32*)g, (lds_u32*)l, 16, 0, 0);
}

// ---------------- fp32 -> bf16 elementwise convert ----------------
__global__ void cvt_f32_bf16(const float* __restrict__ in, u16* __restrict__ out, int n4) {
    int i = blockIdx.x * blockDim.x + threadIdx.x;
    int stride = gridDim.x * blockDim.x;
    for (; i < n4; i += stride) {
        float4 v = ((const float4*)in)[i];
        ushort4 o;
        o.x = f2bf(v.x); o.y = f2bf(v.y); o.z = f2bf(v.z); o.w = f2bf(v.w);
        ((ushort4*)out)[i] = o;
    }
}

// ---------------- transpose fp32 W[K][N] -> bf16 Wt[N][K] ----------------
__global__ void transpose_to_bf16(const float* __restrict__ W, u16* __restrict__ Wt,
                                  int K, int N) {
    __shared__ float tile[32][33];
    int bx = blockIdx.x;
    int by = blockIdx.y;
    int tx = threadIdx.x;
    int ty = threadIdx.y;
    for (int i = 0; i < 4; i++) {
        int kk = ty + i * 8;
        tile[kk][tx] = W[(size_t)(by * 32 + kk) * N + bx * 32 + tx];
    }
    __syncthreads();
    for (int i = 0; i < 4; i++) {
        int nn = ty + i * 8;
        Wt[(size_t)(bx * 32 + nn) * K + by * 32 + tx] = f2bf(tile[tx][nn]);
    }
}

// ================= pipelined 128^2 GEMM core (K=1024, BK=32, 4-buf counted-vmcnt) ======
// 256 threads = 4 waves (2x2); wave computes 64x64 (4x4 16x16x32 frags).
// LDS: 4 buffers x (A 8KB + B 8KB) = 64KB -> 2 blocks/CU.
// Per step: wait vmcnt(8) -> s_barrier -> stage tile k+3 (4 gload16/wave) -> 16 ds_read
// + 16 MFMA. Loads stay in flight across barriers (T3/T4). Granule swizzle slot=lg^(row&3)
// via pre-swizzled global source + swizzled ds_read (both-sides rule).
// Grid: (M/128, N/128) -- mb on x so same-A-panel blocks land on one XCD.

#define GEMM_PRE()                                                                   \
    __shared__ u16 Al[4][4096];                                                      \
    __shared__ u16 Bl[4][4096];                                                      \
    const int mb = blockIdx.x, nb = blockIdx.y;                                      \
    const int tid = threadIdx.x;                                                     \
    const int w = tid >> 6, lane = tid & 63;                                         \
    const int lr = lane & 15, lg = lane >> 4;                                        \
    const int wr = w >> 1, wc = w & 1;                                               \
    f32x4 acc[4][4] = {};                                                            \
    const int srow4 = lane >> 2;                                                     \
    const int sg = ((lane & 3) ^ (srow4 & 3)) * 8;                                   \
    const u16* Ap = A + (size_t)(mb * 128 + w * 32 + srow4) * 1024 + sg;             \
    const u16* Bp = Bt + (size_t)(nb * 128 + w * 32 + srow4) * 1024 + sg;            \
    const int aoff = (wr * 64 + lr) * 32 + ((lg ^ (lr & 3)) * 8);                    \
    const int boff = (wc * 64 + lr) * 32 + ((lg ^ (lr & 3)) * 8);

#define GSTAGE(BUF)                                          \
    do {                                                     \
        gload16(Ap, &Al[BUF][w * 1024]);                     \
        gload16(Ap + 16 * 1024, &Al[BUF][w * 1024 + 512]);   \
        gload16(Bp, &Bl[BUF][w * 1024]);                     \
        gload16(Bp + 16 * 1024, &Bl[BUF][w * 1024 + 512]);   \
        Ap += 32;                                            \
        Bp += 32;                                            \
    } while (0)

#define GCOMPUTE(BUF)                                                                \
    do {                                                                             \
        bf16x8 af[4], bfr[4];                                                        \
        _Pragma("unroll") for (int mf = 0; mf < 4; mf++)                             \
            af[mf] = *(const bf16x8*)(&Al[BUF][aoff + mf * 512]);                    \
        _Pragma("unroll") for (int nf = 0; nf < 4; nf++)                             \
            bfr[nf] = *(const bf16x8*)(&Bl[BUF][boff + nf * 512]);                   \
        __builtin_amdgcn_s_setprio(1);                                               \
        _Pragma("unroll") for (int mf = 0; mf < 4; mf++)                             \
            _Pragma("unroll") for (int nf = 0; nf < 4; nf++)                         \
                acc[mf][nf] = __builtin_amdgcn_mfma_f32_16x16x32_bf16(af[mf], bfr[nf], acc[mf][nf], 0, 0, 0); \
        __builtin_amdgcn_s_setprio(0);                                               \
    } while (0)

#define GSTEP(BUFC, DOSTAGE, VM)                                   \
    do {                                                           \
        asm volatile("s_waitcnt vmcnt(" #VM ")" ::: "memory");     \
        __builtin_amdgcn_s_barrier();                              \
        if (DOSTAGE) GSTAGE(((BUFC) + 3) & 3);                     \
        GCOMPUTE(BUFC);                                            \
        asm volatile("" ::: "memory");                             \
    } while (0)

#define GEMM_LOOP()                                                \
    GSTAGE(0);                                                     \
    GSTAGE(1);                                                     \
    GSTAGE(2);                                                     \
    for (int i = 0; i < 7; i++) {                                  \
        GSTEP(0, 1, 8);                                            \
        GSTEP(1, 1, 8);                                            \
        GSTEP(2, 1, 8);                                            \
        GSTEP(3, 1, 8);                                            \
    }                                                              \
    GSTEP(0, 1, 8);                                                \
    GSTEP(1, 0, 8);                                                \
    GSTEP(2, 0, 4);                                                \
    GSTEP(3, 0, 0);

// ---------------- O-projection (f32 out) ----------------
__global__ __launch_bounds__(256) void gemm128_f32(
    const u16* __restrict__ A, const u16* __restrict__ Bt,
    const float* __restrict__ bias, float* __restrict__ C, int N) {
    GEMM_PRE();
    GEMM_LOOP();
#pragma unroll
    for (int nf = 0; nf < 4; nf++) {
        int n = nb * 128 + wc * 64 + nf * 16 + lr;
        float bval = bias[n];
#pragma unroll
        for (int mf = 0; mf < 4; mf++)
#pragma unroll
            for (int r = 0; r < 4; r++) {
                int m = mb * 128 + wr * 64 + mf * 16 + lg * 4 + r;
                C[(size_t)m * N + n] = acc[mf][nf][r] + bval;
            }
    }
}

// ---------------- fused QKV projection: N = 1024(Q,pre-scaled) + 64(K) + 64(V) ----------
__global__ __launch_bounds__(256) void gemm_proj(
    const u16* __restrict__ A, const u16* __restrict__ Bt,
    const float* __restrict__ bq, const float* __restrict__ bk, const float* __restrict__ bv,
    u16* __restrict__ qout, u16* __restrict__ kout, u16* __restrict__ vout) {
    GEMM_PRE();
    GEMM_LOOP();
#pragma unroll
    for (int nf = 0; nf < 4; nf++) {
        int n = nb * 128 + wc * 64 + nf * 16 + lr;
        float bval = (n < 1024) ? bq[n] : (n < 1088) ? bk[n - 1024] : bv[n - 1088];
#pragma unroll
        for (int mf = 0; mf < 4; mf++)
#pragma unroll
            for (int r = 0; r < 4; r++) {
                int m = mb * 128 + wr * 64 + mf * 16 + lg * 4 + r;
                float val = acc[mf][nf][r] + bval;
                if (n < 1024) {
                    qout[(size_t)m * 1024 + n] = f2bf(val * PSCALE);
                } else if (n < 1088) {
                    kout[(size_t)m * 64 + (n - 1024)] = f2bf(val);
                } else {
                    int bb = m >> 11, t = m & (SS - 1);
                    vout[((size_t)bb * 64 + (n - 1088)) * SS + t] = f2bf(val);
                }
            }
    }
}

// ---------------- flash attention v8 (unchanged from R8) ----------------
#define KVB 64
#define NT (SS / KVB)  // 32

__global__ __launch_bounds__(512) void attn_kernel(
    const u16* __restrict__ q,   // [NTOK][HIDDEN], col = h*64+d (pre-scaled)
    const u16* __restrict__ k,   // [NTOK][64]
    const u16* __restrict__ vt,  // [B][64][S]  (dim-major)
    u16* __restrict__ o) {       // [NTOK][HIDDEN]
    const int qt = blockIdx.x, h = blockIdx.y, b = blockIdx.z;
    const int tid = threadIdx.x;
    const int w = tid >> 6, lane = tid & 63;
    const int lr = lane & 15, lg = lane >> 4;

    __shared__ u16 Kl[4][KVB * 64];   // [kv][d], granule-swizzled
    __shared__ u16 Vl[4][KVB * 64];   // [d][kv], granule-swizzled

    const u16* kbase = k + (size_t)b * SS * HEAD_DIM;
    const u16* vbase = vt + (size_t)b * HEAD_DIM * SS;
    const int rowbase = b * SS + qt * 256 + w * 32;

    const int srow = w * 8 + (lane >> 3);
    const int sc16 = (lane & 7) ^ (srow & 7);
    const u16* kp = kbase + (size_t)srow * HEAD_DIM + sc16 * 8;
    const u16* vp = vbase + (size_t)srow * SS + sc16 * 8;

    bf16x8 qf[2][2];
#pragma unroll
    for (int s = 0; s < 2; s++)
#pragma unroll
        for (int ks = 0; ks < 2; ks++)
            qf[s][ks] = *(const bf16x8*)(q + (size_t)(rowbase + s * 16 + lr) * HIDDEN + h * 64 + ks * 32 + lg * 8);

    bf16x8 onesf;
#pragma unroll
    for (int i = 0; i < 8; i++) onesf[i] = (__bf16)1.0f;

    const int xr = lr & 7;
    const int kvro0 = lr * 64 + ((lg) ^ xr) * 8;       // ks=0 chunk
    const int kvro1 = lr * 64 + ((4 + lg) ^ xr) * 8;   // ks=1 chunk

    f32x4 l_acc[2] = {};
    f32x4 oacc[2][4] = {};

#define VEXP(D, S) asm("v_exp_f32 %0, %1" : "=v"(D) : "v"(S))

#define STAGE(BUF)                            \
    do {                                      \
        gload16(kp, &Kl[BUF][w * 512]);       \
        gload16(vp, &Vl[BUF][w * 512]);       \
        kp += KVB * HEAD_DIM;                 \
        vp += KVB;                            \
    } while (0)

#define CTILE(BUF)                                                                     \
    do {                                                                               \
        f32x4 st0[4] = {}, st1[4] = {};                                                \
        __builtin_amdgcn_s_setprio(1);                                                 \
        _Pragma("unroll") for (int nf = 0; nf < 4; nf++) {                             \
            bf16x8 kf = *(const bf16x8*)(&Kl[BUF][kvro0 + nf * 1024]);                 \
            st0[nf] = __builtin_amdgcn_mfma_f32_16x16x32_bf16(kf, qf[0][0], st0[nf], 0, 0, 0); \
            st1[nf] = __builtin_amdgcn_mfma_f32_16x16x32_bf16(kf, qf[1][0], st1[nf], 0, 0, 0); \
        }                                                                              \
        _Pragma("unroll") for (int nf = 0; nf < 4; nf++) {                             \
            bf16x8 kf = *(const bf16x8*)(&Kl[BUF][kvro1 + nf * 1024]);                 \
            st0[nf] = __builtin_amdgcn_mfma_f32_16x16x32_bf16(kf, qf[0][1], st0[nf], 0, 0, 0); \
            st1[nf] = __builtin_amdgcn_mfma_f32_16x16x32_bf16(kf, qf[1][1], st1[nf], 0, 0, 0); \
        }                                                                              \
        __builtin_amdgcn_s_setprio(0);                                                 \
        /* P = exp2(st) via bare v_exp_f32, packed to bf16 in-register */              \
        uint32_t c0[8], c1[8];                                                         \
        _Pragma("unroll") for (int nf = 0; nf < 4; nf++) {                             \
            float p0, p1, p2, p3, r0, r1, r2, r3;                                      \
            VEXP(p0, st0[nf][0]); VEXP(p1, st0[nf][1]);                                \
            VEXP(p2, st0[nf][2]); VEXP(p3, st0[nf][3]);                                \
            asm("v_cvt_pk_bf16_f32 %0, %1, %2" : "=v"(c0[nf * 2]) : "v"(p0), "v"(p1)); \
            asm("v_cvt_pk_bf16_f32 %0, %1, %2" : "=v"(c0[nf * 2 + 1]) : "v"(p2), "v"(p3)); \
            VEXP(r0, st1[nf][0]); VEXP(r1, st1[nf][1]);                                \
            VEXP(r2, st1[nf][2]); VEXP(r3, st1[nf][3]);                                \
            asm("v_cvt_pk_bf16_f32 %0, %1, %2" : "=v"(c1[nf * 2]) : "v"(r0), "v"(r1)); \
            asm("v_cvt_pk_bf16_f32 %0, %1, %2" : "=v"(c1[nf * 2 + 1]) : "v"(r2), "v"(r3)); \
        }                                                                              \
        /* in-register redistribution + PV + l */                                      \
        _Pragma("unroll") for (int ks = 0; ks < 2; ks++) {                             \
            uint32_t u0 = c0[4 * ks], v0 = c0[4 * ks + 1], x0 = c0[4 * ks + 2], y0 = c0[4 * ks + 3]; \
            uint32_t u1 = c1[4 * ks], v1 = c1[4 * ks + 1], x1 = c1[4 * ks + 2], y1 = c1[4 * ks + 3]; \
            asm("v_permlane32_swap_b32 %0, %1" : "+v"(u0), "+v"(x0));                  \
            asm("v_permlane32_swap_b32 %0, %1" : "+v"(v0), "+v"(y0));                  \
            asm("v_permlane16_swap_b32 %0, %1" : "+v"(u0), "+v"(x0));                  \
            asm("v_permlane16_swap_b32 %0, %1" : "+v"(v0), "+v"(y0));                  \
            asm("v_permlane32_swap_b32 %0, %1" : "+v"(u1), "+v"(x1));                  \
            asm("v_permlane32_swap_b32 %0, %1" : "+v"(v1), "+v"(y1));                  \
            asm("v_permlane16_swap_b32 %0, %1" : "+v"(u1), "+v"(x1));                  \
            asm("v_permlane16_swap_b32 %0, %1" : "+v"(v1), "+v"(y1));                  \
            union { uint32_t wv[4]; bf16x8 v8; } pf0, pf1;                             \
            pf0.wv[0] = u0; pf0.wv[1] = v0; pf0.wv[2] = x0; pf0.wv[3] = y0;            \
            pf1.wv[0] = u1; pf1.wv[1] = v1; pf1.wv[2] = x1; pf1.wv[3] = y1;            \
            const int kvro = ks ? kvro1 : kvro0;                                       \
            __builtin_amdgcn_s_setprio(1);                                             \
            l_acc[0] = __builtin_amdgcn_mfma_f32_16x16x32_bf16(pf0.v8, onesf, l_acc[0], 0, 0, 0); \
            l_acc[1] = __builtin_amdgcn_mfma_f32_16x16x32_bf16(pf1.v8, onesf, l_acc[1], 0, 0, 0); \
            _Pragma("unroll") for (int nf = 0; nf < 4; nf++) {                         \
                bf16x8 vf = *(const bf16x8*)(&Vl[BUF][kvro + nf * 1024]);              \
                oacc[0][nf] = __builtin_amdgcn_mfma_f32_16x16x32_bf16(pf0.v8, vf, oacc[0][nf], 0, 0, 0); \
                oacc[1][nf] = __builtin_amdgcn_mfma_f32_16x16x32_bf16(pf1.v8, vf, oacc[1][nf], 0, 0, 0); \
            }                                                                          \
            __builtin_amdgcn_s_setprio(0);                                             \
        }                                                                              \
    } while (0)

#define STEP(BUFC, DOSTAGE, VM)                                    \
    do {                                                           \
        asm volatile("s_waitcnt vmcnt(" #VM ")" ::: "memory");     \
        __builtin_amdgcn_s_barrier();                              \
        if (DOSTAGE) STAGE(((BUFC) + 3) & 3);                      \
        CTILE(BUFC);                                               \
        asm volatile("" ::: "memory");                             \
    } while (0)

    // prologue: stage tiles 0,1,2
    STAGE(0);
    STAGE(1);
    STAGE(2);

    // main: tiles 0..27 (stage 3..30)
    for (int i = 0; i < 7; i++) {
        STEP(0, 1, 4);
        STEP(1, 1, 4);
        STEP(2, 1, 4);
        STEP(3, 1, 4);
    }
    // tail: tiles 28..31 (stage 31)
    STEP(0, 1, 4);
    STEP(1, 0, 4);
    STEP(2, 0, 2);
    STEP(3, 0, 0);

#undef STEP
#undef STAGE
#undef CTILE
#undef VEXP

    // ---- finalize: O /= l ----
#pragma unroll
    for (int s = 0; s < 2; s++) {
        float li[4];
#pragma unroll
        for (int r = 0; r < 4; r++) li[r] = 1.0f / l_acc[s][r];
#pragma unroll
        for (int nf = 0; nf < 4; nf++)
#pragma unroll
            for (int r = 0; r < 4; r++) {
                float val = oacc[s][nf][r] * li[r];
                o[(size_t)(rowbase + s * 16 + lg * 4 + r) * HIDDEN + h * 64 + nf * 16 + lr] = f2bf(val);
            }
    }
}

extern "C" void kernel_launch(void* const* d_in, const int* in_sizes, int n_in,
                              void* d_out, int out_size, void* d_ws, size_t ws_size,
                              hipStream_t stream) {
    const float* h  = (const float*)d_in[0];
    const float* Wq = (const float*)d_in[1];
    const float* bq = (const float*)d_in[2];
    const float* Wk = (const float*)d_in[3];
    const float* bk = (const float*)d_in[4];
    const float* Wv = (const float*)d_in[5];
    const float* bv = (const float*)d_in[6];
    const float* Wo = (const float*)d_in[7];
    const float* bo = (const float*)d_in[8];

    char* ws = (char*)d_ws;
    u16* hbf  = (u16*)ws; ws += (size_t)NTOK * HIDDEN * 2;
    u16* Wta  = (u16*)ws; ws += (size_t)1152 * HIDDEN * 2;   // Wq^T|Wk^T|Wv^T rows
    u16* Wot  = (u16*)ws; ws += (size_t)HIDDEN * HIDDEN * 2;
    u16* qbf  = (u16*)ws; ws += (size_t)NTOK * HIDDEN * 2;
    u16* kbf  = (u16*)ws; ws += (size_t)NTOK * HEAD_DIM * 2;
    u16* vtb  = (u16*)ws; ws += (size_t)NTOK * HEAD_DIM * 2;
    u16* obf  = (u16*)ws; ws += (size_t)NTOK * HIDDEN * 2;

    cvt_f32_bf16<<<2048, 256, 0, stream>>>(h, hbf, NTOK * HIDDEN / 4);
    transpose_to_bf16<<<dim3(HIDDEN / 32, HIDDEN / 32), dim3(32, 8), 0, stream>>>(Wq, Wta, HIDDEN, HIDDEN);
    transpose_to_bf16<<<dim3(HEAD_DIM / 32, HIDDEN / 32), dim3(32, 8), 0, stream>>>(Wk, Wta + (size_t)1024 * HIDDEN, HIDDEN, HEAD_DIM);
    transpose_to_bf16<<<dim3(HEAD_DIM / 32, HIDDEN / 32), dim3(32, 8), 0, stream>>>(Wv, Wta + (size_t)1088 * HIDDEN, HIDDEN, HEAD_DIM);
    transpose_to_bf16<<<dim3(HIDDEN / 32, HIDDEN / 32), dim3(32, 8), 0, stream>>>(Wo, Wot, HIDDEN, HIDDEN);

    // fused QKV projection (Q pre-scaled by PSCALE); grid (M/128, N/128)
    gemm_proj<<<dim3(NTOK / 128, 1152 / 128), 256, 0, stream>>>(hbf, Wta, bq, bk, bv, qbf, kbf, vtb);

    // attention: 256 q-rows per block, 8 waves x 32 q
    attn_kernel<<<dim3(SS / 256, HEADS, BB), 512, 0, stream>>>(qbf, kbf, vtb, obf);

    // output projection (fp32 out); grid (M/128, N/128)
    gemm128_f32<<<dim3(NTOK / 128, HIDDEN / 128), 256, 0, stream>>>(obf, Wot, bo, (float*)d_out, HIDDEN);
}

// Round 10
// 153.054 us; speedup vs baseline: 1.0599x; 1.0599x over previous
//
#include <hip/hip_runtime.h>
#include <hip/hip_bf16.h>
#include <cstdint>

// MQA: B=4, S=2048, HIDDEN=1024, HEADS=16, HEAD_DIM=64
#define HIDDEN 1024
#define HEADS 16
#define HEAD_DIM 64
#define BB 4
#define SS 2048
#define NTOK (BB * SS)  // 8192

typedef __attribute__((ext_vector_type(8))) __bf16 bf16x8;
typedef __attribute__((ext_vector_type(4))) float f32x4;
typedef unsigned short u16;

// softmax scale folded into Q at projection time: log2(e)/sqrt(HEAD_DIM)
#define PSCALE 0.1803368801111137f

__device__ __forceinline__ u16 f2bf(float x) {
    union { float f; uint32_t u; } v; v.f = x;
    uint32_t r = v.u + 0x7FFF + ((v.u >> 16) & 1);  // RNE
    return (u16)(r >> 16);
}

typedef __attribute__((address_space(3))) uint32_t lds_u32;
typedef __attribute__((address_space(1))) uint32_t glb_u32;
__device__ __forceinline__ void gload16(const u16* g, u16* l) {
    __builtin_amdgcn_global_load_lds((const glb_u32*)g, (lds_u32*)l, 16, 0, 0);
}

// ---------------- fp32 -> bf16 elementwise convert ----------------
__global__ void cvt_f32_bf16(const float* __restrict__ in, u16* __restrict__ out, int n4) {
    int i = blockIdx.x * blockDim.x + threadIdx.x;
    int stride = gridDim.x * blockDim.x;
    for (; i < n4; i += stride) {
        float4 v = ((const float4*)in)[i];
        ushort4 o;
        o.x = f2bf(v.x); o.y = f2bf(v.y); o.z = f2bf(v.z); o.w = f2bf(v.w);
        ((ushort4*)out)[i] = o;
    }
}

// ---------------- transpose fp32 W[K][N] -> bf16 Wt[N][K] ----------------
__global__ void transpose_to_bf16(const float* __restrict__ W, u16* __restrict__ Wt,
                                  int K, int N) {
    __shared__ float tile[32][33];
    int bx = blockIdx.x;
    int by = blockIdx.y;
    int tx = threadIdx.x;
    int ty = threadIdx.y;
    for (int i = 0; i < 4; i++) {
        int kk = ty + i * 8;
        tile[kk][tx] = W[(size_t)(by * 32 + kk) * N + bx * 32 + tx];
    }
    __syncthreads();
    for (int i = 0; i < 4; i++) {
        int nn = ty + i * 8;
        Wt[(size_t)(bx * 32 + nn) * K + by * 32 + tx] = f2bf(tile[tx][nn]);
    }
}

// ---------------- m97-pattern 128^2 GEMM (O-projection, f32 out) — R8 structure ----------------
__global__ __launch_bounds__(256) void gemm128_f32(
    const u16* __restrict__ A, const u16* __restrict__ Bt,
    const float* __restrict__ bias, float* __restrict__ C,
    int M, int N, int K) {
    __shared__ u16 Al[128 * 64];
    __shared__ u16 Bl[128 * 64];
    const int mb = blockIdx.y, nb = blockIdx.x;
    const int tid = threadIdx.x;
    const int w = tid >> 6, lane = tid & 63;
    const int lr = lane & 15, lg = lane >> 4;
    const int wr = w >> 1, wc = w & 1;

    f32x4 acc[4][4] = {};

    const int srow = lane >> 3;
    const int scol = (lane & 7) * 8;
    const u16* Asrc = A + (size_t)(mb * 128 + w * 32 + srow) * K + scol;
    const u16* Bsrc = Bt + (size_t)(nb * 128 + w * 32 + srow) * K + scol;
    u16* Adst = &Al[(w * 32) * 64];
    u16* Bdst = &Bl[(w * 32) * 64];

    for (int k0 = 0; k0 < K; k0 += 64) {
        if (k0) __syncthreads();
#pragma unroll
        for (int i = 0; i < 4; i++) {
            gload16(Asrc + (size_t)(i * 8) * K + k0, Adst + i * 8 * 64);
            gload16(Bsrc + (size_t)(i * 8) * K + k0, Bdst + i * 8 * 64);
        }
        asm volatile("s_waitcnt vmcnt(0)" ::: "memory");
        __syncthreads();

#pragma unroll
        for (int ks = 0; ks < 2; ks++) {
            bf16x8 af[4], bfr[4];
#pragma unroll
            for (int mf = 0; mf < 4; mf++)
                af[mf] = *(const bf16x8*)(&Al[(wr * 64 + mf * 16 + lr) * 64 + ks * 32 + lg * 8]);
#pragma unroll
            for (int nf = 0; nf < 4; nf++)
                bfr[nf] = *(const bf16x8*)(&Bl[(wc * 64 + nf * 16 + lr) * 64 + ks * 32 + lg * 8]);
            __builtin_amdgcn_s_setprio(1);
#pragma unroll
            for (int mf = 0; mf < 4; mf++)
#pragma unroll
                for (int nf = 0; nf < 4; nf++)
                    acc[mf][nf] = __builtin_amdgcn_mfma_f32_16x16x32_bf16(af[mf], bfr[nf], acc[mf][nf], 0, 0, 0);
            __builtin_amdgcn_s_setprio(0);
        }
    }

#pragma unroll
    for (int nf = 0; nf < 4; nf++) {
        int n = nb * 128 + wc * 64 + nf * 16 + lr;
        float bval = bias[n];
#pragma unroll
        for (int mf = 0; mf < 4; mf++)
#pragma unroll
            for (int r = 0; r < 4; r++) {
                int m = mb * 128 + wr * 64 + mf * 16 + lg * 4 + r;
                C[(size_t)m * N + n] = acc[mf][nf][r] + bval;
            }
    }
}

// ---------------- fused QKV projection GEMM: N = 1024(Q) + 64(K) + 64(V) — R8 structure ------
// Q outputs are pre-scaled by PSCALE (softmax scale folded in).
#define NPROJ 1152
__global__ __launch_bounds__(256) void gemm_proj(
    const u16* __restrict__ A, const u16* __restrict__ Bt,
    const float* __restrict__ bq, const float* __restrict__ bk, const float* __restrict__ bv,
    u16* __restrict__ qout, u16* __restrict__ kout, u16* __restrict__ vout) {
    __shared__ u16 Al[128 * 64];
    __shared__ u16 Bl[128 * 64];
    const int mb = blockIdx.y, nb = blockIdx.x;
    const int tid = threadIdx.x;
    const int w = tid >> 6, lane = tid & 63;
    const int lr = lane & 15, lg = lane >> 4;
    const int wr = w >> 1, wc = w & 1;

    f32x4 acc[4][4] = {};

    const int srow = lane >> 3;
    const int scol = (lane & 7) * 8;
    const u16* Asrc = A + (size_t)(mb * 128 + w * 32 + srow) * HIDDEN + scol;
    const u16* Bsrc = Bt + (size_t)(nb * 128 + w * 32 + srow) * HIDDEN + scol;
    u16* Adst = &Al[(w * 32) * 64];
    u16* Bdst = &Bl[(w * 32) * 64];

    for (int k0 = 0; k0 < HIDDEN; k0 += 64) {
        if (k0) __syncthreads();
#pragma unroll
        for (int i = 0; i < 4; i++) {
            gload16(Asrc + (size_t)(i * 8) * HIDDEN + k0, Adst + i * 8 * 64);
            gload16(Bsrc + (size_t)(i * 8) * HIDDEN + k0, Bdst + i * 8 * 64);
        }
        asm volatile("s_waitcnt vmcnt(0)" ::: "memory");
        __syncthreads();

#pragma unroll
        for (int ks = 0; ks < 2; ks++) {
            bf16x8 af[4], bfr[4];
#pragma unroll
            for (int mf = 0; mf < 4; mf++)
                af[mf] = *(const bf16x8*)(&Al[(wr * 64 + mf * 16 + lr) * 64 + ks * 32 + lg * 8]);
#pragma unroll
            for (int nf = 0; nf < 4; nf++)
                bfr[nf] = *(const bf16x8*)(&Bl[(wc * 64 + nf * 16 + lr) * 64 + ks * 32 + lg * 8]);
            __builtin_amdgcn_s_setprio(1);
#pragma unroll
            for (int mf = 0; mf < 4; mf++)
#pragma unroll
                for (int nf = 0; nf < 4; nf++)
                    acc[mf][nf] = __builtin_amdgcn_mfma_f32_16x16x32_bf16(af[mf], bfr[nf], acc[mf][nf], 0, 0, 0);
            __builtin_amdgcn_s_setprio(0);
        }
    }

#pragma unroll
    for (int nf = 0; nf < 4; nf++) {
        int n = nb * 128 + wc * 64 + nf * 16 + lr;
        float bval = (n < 1024) ? bq[n] : (n < 1088) ? bk[n - 1024] : bv[n - 1088];
#pragma unroll
        for (int mf = 0; mf < 4; mf++)
#pragma unroll
            for (int r = 0; r < 4; r++) {
                int m = mb * 128 + wr * 64 + mf * 16 + lg * 4 + r;
                float val = acc[mf][nf][r] + bval;
                if (n < 1024) {
                    qout[(size_t)m * 1024 + n] = f2bf(val * PSCALE);
                } else if (n < 1088) {
                    kout[(size_t)m * 64 + (n - 1024)] = f2bf(val);
                } else {
                    int bb = m >> 11, t = m & (SS - 1);
                    vout[((size_t)bb * 64 + (n - 1088)) * SS + t] = f2bf(val);
                }
            }
    }
}

// ---------------- flash attention v9: 3-buffer (48KB LDS -> 3 blocks/CU), counted-vmcnt ----
// grid: (S/256, HEADS, B), 512 threads (8 waves), wave owns 32 q-rows (2 subs of 16).
// Q pre-scaled by log2(e)/sqrt(Dh); P = exp2(st) via bare v_exp_f32; l via ones-MFMA.
// Pipeline: 3 LDS buffers, 2-deep prefetch, s_waitcnt vmcnt(2) + raw s_barrier; stage
// (t+2)%3 after the barrier (its last reads were at t-1, protected by this barrier).
#define KVB 64
#define NT (SS / KVB)  // 32

__global__ __launch_bounds__(512) void attn_kernel(
    const u16* __restrict__ q,   // [NTOK][HIDDEN], col = h*64+d (pre-scaled)
    const u16* __restrict__ k,   // [NTOK][64]
    const u16* __restrict__ vt,  // [B][64][S]  (dim-major)
    u16* __restrict__ o) {       // [NTOK][HIDDEN]
    const int qt = blockIdx.x, h = blockIdx.y, b = blockIdx.z;
    const int tid = threadIdx.x;
    const int w = tid >> 6, lane = tid & 63;
    const int lr = lane & 15, lg = lane >> 4;

    __shared__ u16 Kl[3][KVB * 64];   // [kv][d], granule-swizzled
    __shared__ u16 Vl[3][KVB * 64];   // [d][kv], granule-swizzled

    const u16* kbase = k + (size_t)b * SS * HEAD_DIM;
    const u16* vbase = vt + (size_t)b * HEAD_DIM * SS;
    const int rowbase = b * SS + qt * 256 + w * 32;

    const int srow = w * 8 + (lane >> 3);
    const int sc16 = (lane & 7) ^ (srow & 7);
    const u16* kp = kbase + (size_t)srow * HEAD_DIM + sc16 * 8;
    const u16* vp = vbase + (size_t)srow * SS + sc16 * 8;

    bf16x8 qf[2][2];
#pragma unroll
    for (int s = 0; s < 2; s++)
#pragma unroll
        for (int ks = 0; ks < 2; ks++)
            qf[s][ks] = *(const bf16x8*)(q + (size_t)(rowbase + s * 16 + lr) * HIDDEN + h * 64 + ks * 32 + lg * 8);

    bf16x8 onesf;
#pragma unroll
    for (int i = 0; i < 8; i++) onesf[i] = (__bf16)1.0f;

    const int xr = lr & 7;
    const int kvro0 = lr * 64 + ((lg) ^ xr) * 8;       // ks=0 chunk
    const int kvro1 = lr * 64 + ((4 + lg) ^ xr) * 8;   // ks=1 chunk

    f32x4 l_acc[2] = {};
    f32x4 oacc[2][4] = {};

#define VEXP(D, S) asm("v_exp_f32 %0, %1" : "=v"(D) : "v"(S))

#define STAGE(BUF)                            \
    do {                                      \
        gload16(kp, &Kl[BUF][w * 512]);       \
        gload16(vp, &Vl[BUF][w * 512]);       \
        kp += KVB * HEAD_DIM;                 \
        vp += KVB;                            \
    } while (0)

#define CTILE(BUF)                                                                     \
    do {                                                                               \
        f32x4 st0[4] = {}, st1[4] = {};                                                \
        __builtin_amdgcn_s_setprio(1);                                                 \
        _Pragma("unroll") for (int nf = 0; nf < 4; nf++) {                             \
            bf16x8 kf = *(const bf16x8*)(&Kl[BUF][kvro0 + nf * 1024]);                 \
            st0[nf] = __builtin_amdgcn_mfma_f32_16x16x32_bf16(kf, qf[0][0], st0[nf], 0, 0, 0); \
            st1[nf] = __builtin_amdgcn_mfma_f32_16x16x32_bf16(kf, qf[1][0], st1[nf], 0, 0, 0); \
        }                                                                              \
        _Pragma("unroll") for (int nf = 0; nf < 4; nf++) {                             \
            bf16x8 kf = *(const bf16x8*)(&Kl[BUF][kvro1 + nf * 1024]);                 \
            st0[nf] = __builtin_amdgcn_mfma_f32_16x16x32_bf16(kf, qf[0][1], st0[nf], 0, 0, 0); \
            st1[nf] = __builtin_amdgcn_mfma_f32_16x16x32_bf16(kf, qf[1][1], st1[nf], 0, 0, 0); \
        }                                                                              \
        __builtin_amdgcn_s_setprio(0);                                                 \
        /* P = exp2(st) via bare v_exp_f32, packed to bf16 in-register */              \
        uint32_t c0[8], c1[8];                                                         \
        _Pragma("unroll") for (int nf = 0; nf < 4; nf++) {                             \
            float p0, p1, p2, p3, r0, r1, r2, r3;                                      \
            VEXP(p0, st0[nf][0]); VEXP(p1, st0[nf][1]);                                \
            VEXP(p2, st0[nf][2]); VEXP(p3, st0[nf][3]);                                \
            asm("v_cvt_pk_bf16_f32 %0, %1, %2" : "=v"(c0[nf * 2]) : "v"(p0), "v"(p1)); \
            asm("v_cvt_pk_bf16_f32 %0, %1, %2" : "=v"(c0[nf * 2 + 1]) : "v"(p2), "v"(p3)); \
            VEXP(r0, st1[nf][0]); VEXP(r1, st1[nf][1]);                                \
            VEXP(r2, st1[nf][2]); VEXP(r3, st1[nf][3]);                                \
            asm("v_cvt_pk_bf16_f32 %0, %1, %2" : "=v"(c1[nf * 2]) : "v"(r0), "v"(r1)); \
            asm("v_cvt_pk_bf16_f32 %0, %1, %2" : "=v"(c1[nf * 2 + 1]) : "v"(r2), "v"(r3)); \
        }                                                                              \
        /* in-register redistribution + PV + l */                                      \
        _Pragma("unroll") for (int ks = 0; ks < 2; ks++) {                             \
            uint32_t u0 = c0[4 * ks], v0 = c0[4 * ks + 1], x0 = c0[4 * ks + 2], y0 = c0[4 * ks + 3]; \
            uint32_t u1 = c1[4 * ks], v1 = c1[4 * ks + 1], x1 = c1[4 * ks + 2], y1 = c1[4 * ks + 3]; \
            asm("v_permlane32_swap_b32 %0, %1" : "+v"(u0), "+v"(x0));                  \
            asm("v_permlane32_swap_b32 %0, %1" : "+v"(v0), "+v"(y0));                  \
            asm("v_permlane16_swap_b32 %0, %1" : "+v"(u0), "+v"(x0));                  \
            asm("v_permlane16_swap_b32 %0, %1" : "+v"(v0), "+v"(y0));                  \
            asm("v_permlane32_swap_b32 %0, %1" : "+v"(u1), "+v"(x1));                  \
            asm("v_permlane32_swap_b32 %0, %1" : "+v"(v1), "+v"(y1));                  \
            asm("v_permlane16_swap_b32 %0, %1" : "+v"(u1), "+v"(x1));                  \
            asm("v_permlane16_swap_b32 %0, %1" : "+v"(v1), "+v"(y1));                  \
            union { uint32_t wv[4]; bf16x8 v8; } pf0, pf1;                             \
            pf0.wv[0] = u0; pf0.wv[1] = v0; pf0.wv[2] = x0; pf0.wv[3] = y0;            \
            pf1.wv[0] = u1; pf1.wv[1] = v1; pf1.wv[2] = x1; pf1.wv[3] = y1;            \
            const int kvro = ks ? kvro1 : kvro0;                                       \
            __builtin_amdgcn_s_setprio(1);                                             \
            l_acc[0] = __builtin_amdgcn_mfma_f32_16x16x32_bf16(pf0.v8, onesf, l_acc[0], 0, 0, 0); \
            l_acc[1] = __builtin_amdgcn_mfma_f32_16x16x32_bf16(pf1.v8, onesf, l_acc[1], 0, 0, 0); \
            _Pragma("unroll") for (int nf = 0; nf < 4; nf++) {                         \
                bf16x8 vf = *(const bf16x8*)(&Vl[BUF][kvro + nf * 1024]);              \
                oacc[0][nf] = __builtin_amdgcn_mfma_f32_16x16x32_bf16(pf0.v8, vf, oacc[0][nf], 0, 0, 0); \
                oacc[1][nf] = __builtin_amdgcn_mfma_f32_16x16x32_bf16(pf1.v8, vf, oacc[1][nf], 0, 0, 0); \
            }                                                                          \
            __builtin_amdgcn_s_setprio(0);                                             \
        }                                                                              \
    } while (0)

#define STEP(BUFC, DOSTAGE, VM)                                    \
    do {                                                           \
        asm volatile("s_waitcnt vmcnt(" #VM ")" ::: "memory");     \
        __builtin_amdgcn_s_barrier();                              \
        if (DOSTAGE) STAGE(((BUFC) + 2) % 3);                      \
        CTILE(BUFC);                                               \
        asm volatile("" ::: "memory");                             \
    } while (0)

    // prologue: stage tiles 0,1
    STAGE(0);
    STAGE(1);

    // main: tiles 0..29 (stage 2..31)
    for (int i = 0; i < 10; i++) {
        STEP(0, 1, 2);
        STEP(1, 1, 2);
        STEP(2, 1, 2);
    }
    // tail: tiles 30,31 (no stage)
    STEP(0, 0, 2);
    STEP(1, 0, 0);

#undef STEP
#undef STAGE
#undef CTILE
#undef VEXP

    // ---- finalize: O /= l ----
#pragma unroll
    for (int s = 0; s < 2; s++) {
        float li[4];
#pragma unroll
        for (int r = 0; r < 4; r++) li[r] = 1.0f / l_acc[s][r];
#pragma unroll
        for (int nf = 0; nf < 4; nf++)
#pragma unroll
            for (int r = 0; r < 4; r++) {
                float val = oacc[s][nf][r] * li[r];
                o[(size_t)(rowbase + s * 16 + lg * 4 + r) * HIDDEN + h * 64 + nf * 16 + lr] = f2bf(val);
            }
    }
}

extern "C" void kernel_launch(void* const* d_in, const int* in_sizes, int n_in,
                              void* d_out, int out_size, void* d_ws, size_t ws_size,
                              hipStream_t stream) {
    const float* h  = (const float*)d_in[0];
    const float* Wq = (const float*)d_in[1];
    const float* bq = (const float*)d_in[2];
    const float* Wk = (const float*)d_in[3];
    const float* bk = (const float*)d_in[4];
    const float* Wv = (const float*)d_in[5];
    const float* bv = (const float*)d_in[6];
    const float* Wo = (const float*)d_in[7];
    const float* bo = (const float*)d_in[8];

    char* ws = (char*)d_ws;
    u16* hbf  = (u16*)ws; ws += (size_t)NTOK * HIDDEN * 2;
    u16* Wta  = (u16*)ws; ws += (size_t)NPROJ * HIDDEN * 2;   // Wq^T|Wk^T|Wv^T rows
    u16* Wot  = (u16*)ws; ws += (size_t)HIDDEN * HIDDEN * 2;
    u16* qbf  = (u16*)ws; ws += (size_t)NTOK * HIDDEN * 2;
    u16* kbf  = (u16*)ws; ws += (size_t)NTOK * HEAD_DIM * 2;
    u16* vtb  = (u16*)ws; ws += (size_t)NTOK * HEAD_DIM * 2;
    u16* obf  = (u16*)ws; ws += (size_t)NTOK * HIDDEN * 2;

    cvt_f32_bf16<<<2048, 256, 0, stream>>>(h, hbf, NTOK * HIDDEN / 4);
    transpose_to_bf16<<<dim3(HIDDEN / 32, HIDDEN / 32), dim3(32, 8), 0, stream>>>(Wq, Wta, HIDDEN, HIDDEN);
    transpose_to_bf16<<<dim3(HEAD_DIM / 32, HIDDEN / 32), dim3(32, 8), 0, stream>>>(Wk, Wta + (size_t)1024 * HIDDEN, HIDDEN, HEAD_DIM);
    transpose_to_bf16<<<dim3(HEAD_DIM / 32, HIDDEN / 32), dim3(32, 8), 0, stream>>>(Wv, Wta + (size_t)1088 * HIDDEN, HIDDEN, HEAD_DIM);
    transpose_to_bf16<<<dim3(HIDDEN / 32, HIDDEN / 32), dim3(32, 8), 0, stream>>>(Wo, Wot, HIDDEN, HIDDEN);

    // fused QKV projection (Q pre-scaled by PSCALE)
    gemm_proj<<<dim3(NPROJ / 128, NTOK / 128), 256, 0, stream>>>(hbf, Wta, bq, bk, bv, qbf, kbf, vtb);

    // attention: 256 q-rows per block, 8 waves x 32 q
    attn_kernel<<<dim3(SS / 256, HEADS, BB), 512, 0, stream>>>(qbf, kbf, vtb, obf);

    // output projection (fp32 out)
    gemm128_f32<<<dim3(HIDDEN / 128, NTOK / 128), 256, 0, stream>>>(obf, Wot, bo, (float*)d_out, NTOK, HIDDEN, HIDDEN);
}

// Round 11
// 146.034 us; speedup vs baseline: 1.1108x; 1.0481x over previous
//
#include <hip/hip_runtime.h>
#include <hip/hip_bf16.h>
#include <cstdint>

// MQA: B=4, S=2048, HIDDEN=1024, HEADS=16, HEAD_DIM=64
#define HIDDEN 1024
#define HEADS 16
#define HEAD_DIM 64
#define BB 4
#define SS 2048
#define NTOK (BB * SS)  // 8192

typedef __attribute__((ext_vector_type(8))) __bf16 bf16x8;
typedef __attribute__((ext_vector_type(4))) float f32x4;
typedef unsigned short u16;

// softmax scale folded into Q at projection time: log2(e)/sqrt(HEAD_DIM)
#define PSCALE 0.1803368801111137f

__device__ __forceinline__ u16 f2bf(float x) {
    union { float f; uint32_t u; } v; v.f = x;
    uint32_t r = v.u + 0x7FFF + ((v.u >> 16) & 1);  // RNE
    return (u16)(r >> 16);
}

typedef __attribute__((address_space(3))) uint32_t lds_u32;
typedef __attribute__((address_space(1))) uint32_t glb_u32;
__device__ __forceinline__ void gload16(const u16* g, u16* l) {
    __builtin_amdgcn_global_load_lds((const glb_u32*)g, (lds_u32*)l, 16, 0, 0);
}

// ---------------- fp32 -> bf16 elementwise convert ----------------
__global__ void cvt_f32_bf16(const float* __restrict__ in, u16* __restrict__ out, int n4) {
    int i = blockIdx.x * blockDim.x + threadIdx.x;
    int stride = gridDim.x * blockDim.x;
    for (; i < n4; i += stride) {
        float4 v = ((const float4*)in)[i];
        ushort4 o;
        o.x = f2bf(v.x); o.y = f2bf(v.y); o.z = f2bf(v.z); o.w = f2bf(v.w);
        ((ushort4*)out)[i] = o;
    }
}

// ---------------- batched transpose fp32 W[K][N] -> bf16 Wt[N][K] (4 matrices) ----------------
// z=0: Wq (N=1024), z=1: Wk (N=64), z=2: Wv (N=64), z=3: Wo (N=1024). K=1024 for all.
__global__ void transpose4_to_bf16(const float* __restrict__ Wq, const float* __restrict__ Wk,
                                   const float* __restrict__ Wv, const float* __restrict__ Wo,
                                   u16* __restrict__ Wta, u16* __restrict__ Wot) {
    __shared__ float tile[32][33];
    const int z = blockIdx.z;
    const int Nz = (z == 1 || z == 2) ? 64 : 1024;
    const int bx = blockIdx.x;
    if (bx * 32 >= Nz) return;
    const float* W = (z == 0) ? Wq : (z == 1) ? Wk : (z == 2) ? Wv : Wo;
    u16* Wt = (z == 0) ? Wta : (z == 1) ? (Wta + (size_t)1024 * HIDDEN)
              : (z == 2) ? (Wta + (size_t)1088 * HIDDEN) : Wot;
    const int by = blockIdx.y;
    const int tx = threadIdx.x;
    const int ty = threadIdx.y;
    for (int i = 0; i < 4; i++) {
        int kk = ty + i * 8;
        tile[kk][tx] = W[(size_t)(by * 32 + kk) * Nz + bx * 32 + tx];
    }
    __syncthreads();
    for (int i = 0; i < 4; i++) {
        int nn = ty + i * 8;
        Wt[(size_t)(bx * 32 + nn) * 1024 + by * 32 + tx] = f2bf(tile[tx][nn]);
    }
}

// ---------------- m97-pattern 128^2 GEMM (O-projection, f32 out) — R8 structure ----------------
__global__ __launch_bounds__(256) void gemm128_f32(
    const u16* __restrict__ A, const u16* __restrict__ Bt,
    const float* __restrict__ bias, float* __restrict__ C,
    int M, int N, int K) {
    __shared__ u16 Al[128 * 64];
    __shared__ u16 Bl[128 * 64];
    const int mb = blockIdx.y, nb = blockIdx.x;
    const int tid = threadIdx.x;
    const int w = tid >> 6, lane = tid & 63;
    const int lr = lane & 15, lg = lane >> 4;
    const int wr = w >> 1, wc = w & 1;

    f32x4 acc[4][4] = {};

    const int srow = lane >> 3;
    const int scol = (lane & 7) * 8;
    const u16* Asrc = A + (size_t)(mb * 128 + w * 32 + srow) * K + scol;
    const u16* Bsrc = Bt + (size_t)(nb * 128 + w * 32 + srow) * K + scol;
    u16* Adst = &Al[(w * 32) * 64];
    u16* Bdst = &Bl[(w * 32) * 64];

    for (int k0 = 0; k0 < K; k0 += 64) {
        if (k0) __syncthreads();
#pragma unroll
        for (int i = 0; i < 4; i++) {
            gload16(Asrc + (size_t)(i * 8) * K + k0, Adst + i * 8 * 64);
            gload16(Bsrc + (size_t)(i * 8) * K + k0, Bdst + i * 8 * 64);
        }
        asm volatile("s_waitcnt vmcnt(0)" ::: "memory");
        __syncthreads();

#pragma unroll
        for (int ks = 0; ks < 2; ks++) {
            bf16x8 af[4], bfr[4];
#pragma unroll
            for (int mf = 0; mf < 4; mf++)
                af[mf] = *(const bf16x8*)(&Al[(wr * 64 + mf * 16 + lr) * 64 + ks * 32 + lg * 8]);
#pragma unroll
            for (int nf = 0; nf < 4; nf++)
                bfr[nf] = *(const bf16x8*)(&Bl[(wc * 64 + nf * 16 + lr) * 64 + ks * 32 + lg * 8]);
            __builtin_amdgcn_s_setprio(1);
#pragma unroll
            for (int mf = 0; mf < 4; mf++)
#pragma unroll
                for (int nf = 0; nf < 4; nf++)
                    acc[mf][nf] = __builtin_amdgcn_mfma_f32_16x16x32_bf16(af[mf], bfr[nf], acc[mf][nf], 0, 0, 0);
            __builtin_amdgcn_s_setprio(0);
        }
    }

#pragma unroll
    for (int nf = 0; nf < 4; nf++) {
        int n = nb * 128 + wc * 64 + nf * 16 + lr;
        float bval = bias[n];
#pragma unroll
        for (int mf = 0; mf < 4; mf++)
#pragma unroll
            for (int r = 0; r < 4; r++) {
                int m = mb * 128 + wr * 64 + mf * 16 + lg * 4 + r;
                C[(size_t)m * N + n] = acc[mf][nf][r] + bval;
            }
    }
}

// ---------------- fused QKV projection GEMM: N = 1024(Q) + 64(K) + 64(V) — R8 structure ------
#define NPROJ 1152
__global__ __launch_bounds__(256) void gemm_proj(
    const u16* __restrict__ A, const u16* __restrict__ Bt,
    const float* __restrict__ bq, const float* __restrict__ bk, const float* __restrict__ bv,
    u16* __restrict__ qout, u16* __restrict__ kout, u16* __restrict__ vout) {
    __shared__ u16 Al[128 * 64];
    __shared__ u16 Bl[128 * 64];
    const int mb = blockIdx.y, nb = blockIdx.x;
    const int tid = threadIdx.x;
    const int w = tid >> 6, lane = tid & 63;
    const int lr = lane & 15, lg = lane >> 4;
    const int wr = w >> 1, wc = w & 1;

    f32x4 acc[4][4] = {};

    const int srow = lane >> 3;
    const int scol = (lane & 7) * 8;
    const u16* Asrc = A + (size_t)(mb * 128 + w * 32 + srow) * HIDDEN + scol;
    const u16* Bsrc = Bt + (size_t)(nb * 128 + w * 32 + srow) * HIDDEN + scol;
    u16* Adst = &Al[(w * 32) * 64];
    u16* Bdst = &Bl[(w * 32) * 64];

    for (int k0 = 0; k0 < HIDDEN; k0 += 64) {
        if (k0) __syncthreads();
#pragma unroll
        for (int i = 0; i < 4; i++) {
            gload16(Asrc + (size_t)(i * 8) * HIDDEN + k0, Adst + i * 8 * 64);
            gload16(Bsrc + (size_t)(i * 8) * HIDDEN + k0, Bdst + i * 8 * 64);
        }
        asm volatile("s_waitcnt vmcnt(0)" ::: "memory");
        __syncthreads();

#pragma unroll
        for (int ks = 0; ks < 2; ks++) {
            bf16x8 af[4], bfr[4];
#pragma unroll
            for (int mf = 0; mf < 4; mf++)
                af[mf] = *(const bf16x8*)(&Al[(wr * 64 + mf * 16 + lr) * 64 + ks * 32 + lg * 8]);
#pragma unroll
            for (int nf = 0; nf < 4; nf++)
                bfr[nf] = *(const bf16x8*)(&Bl[(wc * 64 + nf * 16 + lr) * 64 + ks * 32 + lg * 8]);
            __builtin_amdgcn_s_setprio(1);
#pragma unroll
            for (int mf = 0; mf < 4; mf++)
#pragma unroll
                for (int nf = 0; nf < 4; nf++)
                    acc[mf][nf] = __builtin_amdgcn_mfma_f32_16x16x32_bf16(af[mf], bfr[nf], acc[mf][nf], 0, 0, 0);
            __builtin_amdgcn_s_setprio(0);
        }
    }

#pragma unroll
    for (int nf = 0; nf < 4; nf++) {
        int n = nb * 128 + wc * 64 + nf * 16 + lr;
        float bval = (n < 1024) ? bq[n] : (n < 1088) ? bk[n - 1024] : bv[n - 1088];
#pragma unroll
        for (int mf = 0; mf < 4; mf++)
#pragma unroll
            for (int r = 0; r < 4; r++) {
                int m = mb * 128 + wr * 64 + mf * 16 + lg * 4 + r;
                float val = acc[mf][nf][r] + bval;
                if (n < 1024) {
                    qout[(size_t)m * 1024 + n] = f2bf(val * PSCALE);
                } else if (n < 1088) {
                    kout[(size_t)m * 64 + (n - 1024)] = f2bf(val);
                } else {
                    int bb = m >> 11, t = m & (SS - 1);
                    vout[((size_t)bb * 64 + (n - 1088)) * SS + t] = f2bf(val);
                }
            }
    }
}

// ---------------- flash attention v10: cross-tile pipeline PV(t-1) || QK(t), EXPPERM(t) ----
// grid: (S/256, HEADS, B), 512 threads (8 waves), wave owns 32 q-rows (2 subs of 16).
// P-fragment state pw[16] carries across iterations: PV(t-1) consumes pw, then QK(t)+
// EXPPERM(t) rewrite it. MFMA clusters of consecutive tiles run back-to-back; the exp
// TRANS burst overlaps other-block MFMA via CU drift. 4 LDS buffers, counted vmcnt(2),
// one raw s_barrier per iteration; stage (t+2)%4 issued after the barrier.
#define KVB 64
#define NT (SS / KVB)  // 32

__global__ __launch_bounds__(512) void attn_kernel(
    const u16* __restrict__ q,   // [NTOK][HIDDEN], col = h*64+d (pre-scaled)
    const u16* __restrict__ k,   // [NTOK][64]
    const u16* __restrict__ vt,  // [B][64][S]  (dim-major)
    u16* __restrict__ o) {       // [NTOK][HIDDEN]
    const int qt = blockIdx.x, h = blockIdx.y, b = blockIdx.z;
    const int tid = threadIdx.x;
    const int w = tid >> 6, lane = tid & 63;
    const int lr = lane & 15, lg = lane >> 4;

    __shared__ u16 Kl[4][KVB * 64];   // [kv][d], granule-swizzled
    __shared__ u16 Vl[4][KVB * 64];   // [d][kv], granule-swizzled

    const u16* kbase = k + (size_t)b * SS * HEAD_DIM;
    const u16* vbase = vt + (size_t)b * HEAD_DIM * SS;
    const int rowbase = b * SS + qt * 256 + w * 32;

    const int srow = w * 8 + (lane >> 3);
    const int sc16 = (lane & 7) ^ (srow & 7);
    const u16* kp = kbase + (size_t)srow * HEAD_DIM + sc16 * 8;
    const u16* vp = vbase + (size_t)srow * SS + sc16 * 8;

    bf16x8 qf[2][2];
#pragma unroll
    for (int s = 0; s < 2; s++)
#pragma unroll
        for (int ks = 0; ks < 2; ks++)
            qf[s][ks] = *(const bf16x8*)(q + (size_t)(rowbase + s * 16 + lr) * HIDDEN + h * 64 + ks * 32 + lg * 8);

    bf16x8 onesf;
#pragma unroll
    for (int i = 0; i < 8; i++) onesf[i] = (__bf16)1.0f;

    const int xr = lr & 7;
    const int kvro0 = lr * 64 + ((lg) ^ xr) * 8;       // ks=0 chunk
    const int kvro1 = lr * 64 + ((4 + lg) ^ xr) * 8;   // ks=1 chunk

    f32x4 l_acc[2] = {};
    f32x4 oacc[2][4] = {};
    uint32_t pw[16];   // P fragments: pw[s*8 + ks*4 + j]

#define VEXP(D, S) asm("v_exp_f32 %0, %1" : "=v"(D) : "v"(S))

#define STAGE(BUF)                            \
    do {                                      \
        gload16(kp, &Kl[BUF][w * 512]);       \
        gload16(vp, &Vl[BUF][w * 512]);       \
        kp += KVB * HEAD_DIM;                 \
        vp += KVB;                            \
    } while (0)

// QK^T + exp + cvt + permlane -> pw (tile in Kl[BUF])
#define QKEXP(BUF)                                                                     \
    do {                                                                               \
        f32x4 st0[4] = {}, st1[4] = {};                                                \
        __builtin_amdgcn_s_setprio(1);                                                 \
        _Pragma("unroll") for (int nf = 0; nf < 4; nf++) {                             \
            bf16x8 kf = *(const bf16x8*)(&Kl[BUF][kvro0 + nf * 1024]);                 \
            st0[nf] = __builtin_amdgcn_mfma_f32_16x16x32_bf16(kf, qf[0][0], st0[nf], 0, 0, 0); \
            st1[nf] = __builtin_amdgcn_mfma_f32_16x16x32_bf16(kf, qf[1][0], st1[nf], 0, 0, 0); \
        }                                                                              \
        _Pragma("unroll") for (int nf = 0; nf < 4; nf++) {                             \
            bf16x8 kf = *(const bf16x8*)(&Kl[BUF][kvro1 + nf * 1024]);                 \
            st0[nf] = __builtin_amdgcn_mfma_f32_16x16x32_bf16(kf, qf[0][1], st0[nf], 0, 0, 0); \
            st1[nf] = __builtin_amdgcn_mfma_f32_16x16x32_bf16(kf, qf[1][1], st1[nf], 0, 0, 0); \
        }                                                                              \
        __builtin_amdgcn_s_setprio(0);                                                 \
        uint32_t c0[8], c1[8];                                                         \
        _Pragma("unroll") for (int nf = 0; nf < 4; nf++) {                             \
            float p0, p1, p2, p3, r0, r1, r2, r3;                                      \
            VEXP(p0, st0[nf][0]); VEXP(p1, st0[nf][1]);                                \
            VEXP(p2, st0[nf][2]); VEXP(p3, st0[nf][3]);                                \
            asm("v_cvt_pk_bf16_f32 %0, %1, %2" : "=v"(c0[nf * 2]) : "v"(p0), "v"(p1)); \
            asm("v_cvt_pk_bf16_f32 %0, %1, %2" : "=v"(c0[nf * 2 + 1]) : "v"(p2), "v"(p3)); \
            VEXP(r0, st1[nf][0]); VEXP(r1, st1[nf][1]);                                \
            VEXP(r2, st1[nf][2]); VEXP(r3, st1[nf][3]);                                \
            asm("v_cvt_pk_bf16_f32 %0, %1, %2" : "=v"(c1[nf * 2]) : "v"(r0), "v"(r1)); \
            asm("v_cvt_pk_bf16_f32 %0, %1, %2" : "=v"(c1[nf * 2 + 1]) : "v"(r2), "v"(r3)); \
        }                                                                              \
        _Pragma("unroll") for (int ks = 0; ks < 2; ks++) {                             \
            uint32_t u0 = c0[4 * ks], v0 = c0[4 * ks + 1], x0 = c0[4 * ks + 2], y0 = c0[4 * ks + 3]; \
            uint32_t u1 = c1[4 * ks], v1 = c1[4 * ks + 1], x1 = c1[4 * ks + 2], y1 = c1[4 * ks + 3]; \
            asm("v_permlane32_swap_b32 %0, %1" : "+v"(u0), "+v"(x0));                  \
            asm("v_permlane32_swap_b32 %0, %1" : "+v"(v0), "+v"(y0));                  \
            asm("v_permlane16_swap_b32 %0, %1" : "+v"(u0), "+v"(x0));                  \
            asm("v_permlane16_swap_b32 %0, %1" : "+v"(v0), "+v"(y0));                  \
            asm("v_permlane32_swap_b32 %0, %1" : "+v"(u1), "+v"(x1));                  \
            asm("v_permlane32_swap_b32 %0, %1" : "+v"(v1), "+v"(y1));                  \
            asm("v_permlane16_swap_b32 %0, %1" : "+v"(u1), "+v"(x1));                  \
            asm("v_permlane16_swap_b32 %0, %1" : "+v"(v1), "+v"(y1));                  \
            pw[ks * 4 + 0] = u0; pw[ks * 4 + 1] = v0;                                  \
            pw[ks * 4 + 2] = x0; pw[ks * 4 + 3] = y0;                                  \
            pw[8 + ks * 4 + 0] = u1; pw[8 + ks * 4 + 1] = v1;                          \
            pw[8 + ks * 4 + 2] = x1; pw[8 + ks * 4 + 3] = y1;                          \
        }                                                                              \
    } while (0)

// PV + l accumulation using pw (tile in Vl[BUF])
#define PVACC(BUF)                                                                     \
    do {                                                                               \
        union { uint32_t wv[4]; bf16x8 v8; } pf0, pf1;                                 \
        __builtin_amdgcn_s_setprio(1);                                                 \
        _Pragma("unroll") for (int ks = 0; ks < 2; ks++) {                             \
            pf0.wv[0] = pw[ks * 4 + 0]; pf0.wv[1] = pw[ks * 4 + 1];                    \
            pf0.wv[2] = pw[ks * 4 + 2]; pf0.wv[3] = pw[ks * 4 + 3];                    \
            pf1.wv[0] = pw[8 + ks * 4 + 0]; pf1.wv[1] = pw[8 + ks * 4 + 1];            \
            pf1.wv[2] = pw[8 + ks * 4 + 2]; pf1.wv[3] = pw[8 + ks * 4 + 3];            \
            const int kvro = ks ? kvro1 : kvro0;                                       \
            l_acc[0] = __builtin_amdgcn_mfma_f32_16x16x32_bf16(pf0.v8, onesf, l_acc[0], 0, 0, 0); \
            l_acc[1] = __builtin_amdgcn_mfma_f32_16x16x32_bf16(pf1.v8, onesf, l_acc[1], 0, 0, 0); \
            _Pragma("unroll") for (int nf = 0; nf < 4; nf++) {                         \
                bf16x8 vf = *(const bf16x8*)(&Vl[BUF][kvro + nf * 1024]);              \
                oacc[0][nf] = __builtin_amdgcn_mfma_f32_16x16x32_bf16(pf0.v8, vf, oacc[0][nf], 0, 0, 0); \
                oacc[1][nf] = __builtin_amdgcn_mfma_f32_16x16x32_bf16(pf1.v8, vf, oacc[1][nf], 0, 0, 0); \
            }                                                                          \
        }                                                                              \
        __builtin_amdgcn_s_setprio(0);                                                 \
    } while (0)

// iteration t: PV(t-1) then QK+EXPPERM(t); stage (t+2)%4
#define ITER(BPV, BQK, BST, DOSTAGE, VM)                           \
    do {                                                           \
        asm volatile("s_waitcnt vmcnt(" #VM ")" ::: "memory");     \
        __builtin_amdgcn_s_barrier();                              \
        if (DOSTAGE) STAGE(BST);                                   \
        PVACC(BPV);                                                \
        QKEXP(BQK);                                                \
        asm volatile("" ::: "memory");                             \
    } while (0)

    // prologue: stage 0,1; QK(0); stage 2
    STAGE(0);
    STAGE(1);
    asm volatile("s_waitcnt vmcnt(2)" ::: "memory");
    __builtin_amdgcn_s_barrier();
    STAGE(2);
    QKEXP(0);

    // main: t = 1..28 (7 groups of 4); stages 3..30
    for (int i = 0; i < 7; i++) {
        ITER(0, 1, 3, 1, 2);   // t=1
        ITER(1, 2, 0, 1, 2);   // t=2
        ITER(2, 3, 1, 1, 2);   // t=3
        ITER(3, 0, 2, 1, 2);   // t=4
    }
    // t=29 (stage 31), t=30, t=31
    ITER(0, 1, 3, 1, 2);
    ITER(1, 2, 3, 0, 2);
    ITER(2, 3, 3, 0, 0);
    // tail: PV(31) in buf 3
    PVACC(3);

#undef ITER
#undef STAGE
#undef QKEXP
#undef PVACC
#undef VEXP

    // ---- finalize: O /= l ----
#pragma unroll
    for (int s = 0; s < 2; s++) {
        float li[4];
#pragma unroll
        for (int r = 0; r < 4; r++) li[r] = 1.0f / l_acc[s][r];
#pragma unroll
        for (int nf = 0; nf < 4; nf++)
#pragma unroll
            for (int r = 0; r < 4; r++) {
                float val = oacc[s][nf][r] * li[r];
                o[(size_t)(rowbase + s * 16 + lg * 4 + r) * HIDDEN + h * 64 + nf * 16 + lr] = f2bf(val);
            }
    }
}

extern "C" void kernel_launch(void* const* d_in, const int* in_sizes, int n_in,
                              void* d_out, int out_size, void* d_ws, size_t ws_size,
                              hipStream_t stream) {
    const float* h  = (const float*)d_in[0];
    const float* Wq = (const float*)d_in[1];
    const float* bq = (const float*)d_in[2];
    const float* Wk = (const float*)d_in[3];
    const float* bk = (const float*)d_in[4];
    const float* Wv = (const float*)d_in[5];
    const float* bv = (const float*)d_in[6];
    const float* Wo = (const float*)d_in[7];
    const float* bo = (const float*)d_in[8];

    char* ws = (char*)d_ws;
    u16* hbf  = (u16*)ws; ws += (size_t)NTOK * HIDDEN * 2;
    u16* Wta  = (u16*)ws; ws += (size_t)NPROJ * HIDDEN * 2;   // Wq^T|Wk^T|Wv^T rows
    u16* Wot  = (u16*)ws; ws += (size_t)HIDDEN * HIDDEN * 2;
    u16* qbf  = (u16*)ws; ws += (size_t)NTOK * HIDDEN * 2;
    u16* kbf  = (u16*)ws; ws += (size_t)NTOK * HEAD_DIM * 2;
    u16* vtb  = (u16*)ws; ws += (size_t)NTOK * HEAD_DIM * 2;
    u16* obf  = (u16*)ws; ws += (size_t)NTOK * HIDDEN * 2;

    cvt_f32_bf16<<<2048, 256, 0, stream>>>(h, hbf, NTOK * HIDDEN / 4);
    transpose4_to_bf16<<<dim3(32, 32, 4), dim3(32, 8), 0, stream>>>(Wq, Wk, Wv, Wo, Wta, Wot);

    // fused QKV projection (Q pre-scaled by PSCALE)
    gemm_proj<<<dim3(NPROJ / 128, NTOK / 128), 256, 0, stream>>>(hbf, Wta, bq, bk, bv, qbf, kbf, vtb);

    // attention: 256 q-rows per block, 8 waves x 32 q
    attn_kernel<<<dim3(SS / 256, HEADS, BB), 512, 0, stream>>>(qbf, kbf, vtb, obf);

    // output projection (fp32 out)
    gemm128_f32<<<dim3(HIDDEN / 128, NTOK / 128), 256, 0, stream>>>(obf, Wot, bo, (float*)d_out, NTOK, HIDDEN, HIDDEN);
}